// Round 6
// baseline (374.708 us; speedup 1.0000x reference)
//
#include <hip/hip_runtime.h>
#include <hip/hip_bf16.h>
#include <cstdint>

#define B_  16
#define S_  577
#define D_  768
#define H_  12
#define SP  640           // padded S
#define M_  (B_*S_)       // 9232
#define MP  9344          // padded M (73*128)
#define N_  2304          // combined QKV output dim
#define SCS 664           // sc LDS stride in shorts
#define QSCALE 0.18033688011112042f   // 0.125 * log2(e): scores land in log2 domain

typedef __attribute__((ext_vector_type(8))) short short8;
typedef __attribute__((ext_vector_type(4))) float f32x4;

static __device__ __forceinline__ unsigned short f2bf(float f) {
    uint32_t u = __builtin_bit_cast(uint32_t, f);
    uint32_t r = u + 0x7fffu + ((u >> 16) & 1u);
    return (unsigned short)(r >> 16);
}
static __device__ __forceinline__ float bf2f(unsigned short u) {
    uint32_t x = ((uint32_t)u) << 16;
    return __builtin_bit_cast(float, x);
}

typedef unsigned int u32;
typedef __attribute__((address_space(3))) u32 lds_u32;
typedef __attribute__((address_space(1))) const u32 gbl_u32;
static __device__ __forceinline__ void gll16(const void* g, void* l) {
    __builtin_amdgcn_global_load_lds((gbl_u32*)g, (lds_u32*)l, 16, 0, 0);
}

// Fragment layouts (shorts), d = within-head dim (0..63):
//  Qf: (((b*40+qc)*12+h)*2+dh)*512 + ql*32 + dg*8 + db      q=qc*16+ql, d=dh*32+dg*8+db
//  Kf: (((b*12+h)*10+c)*4+kq)*2+dh)*512 + kl*32 + dg*8 + db key=c*64+kq*16+kl
//  Vf: ((b*12+h)*20+kk)*4+wq)*512 + dl*32 + kg*8 + kb       key=kk*32+kg*8+kb, d=wq*16+dl
// Each attn wave fragment load = contiguous 1KB.

// ---------- prep: fp32 -> bf16 of X (zero pad rows) and W; zero Vf pad keys ----------
__global__ __launch_bounds__(256) void prep(
    const float* __restrict__ X,
    const float* __restrict__ Wq, const float* __restrict__ Wk, const float* __restrict__ Wv,
    unsigned short* __restrict__ Xb, unsigned short* __restrict__ Wb,
    unsigned short* __restrict__ Vf)
{
    const int NT1 = MP * 192;
    const int NT2 = N_ * 192;
    const int VPAD = 192 * 64 * 63;            // (b*h) * d * padkeys
    const int total = NT1 + NT2 + VPAD;
    const int stride = gridDim.x * 256;
    for (int i = blockIdx.x * 256 + threadIdx.x; i < total; i += stride) {
        if (i < NT1) {
            int row = i / 192, c4 = i - row * 192;
            uint2 out = make_uint2(0u, 0u);
            if (row < M_) {
                float4 v = *(const float4*)(X + (size_t)row * 768 + c4 * 4);
                unsigned short p[4] = { f2bf(v.x), f2bf(v.y), f2bf(v.z), f2bf(v.w) };
                out = *(uint2*)p;
            }
            *(uint2*)(Xb + (size_t)row * 768 + c4 * 4) = out;
        } else if (i < NT1 + NT2) {
            int j = i - NT1;
            int row = j / 192, c4 = j - row * 192;
            const float* src = (row < 768) ? (Wq + (size_t)row * 768)
                             : (row < 1536) ? (Wk + (size_t)(row - 768) * 768)
                                            : (Wv + (size_t)(row - 1536) * 768);
            float4 v = *(const float4*)(src + c4 * 4);
            unsigned short p[4] = { f2bf(v.x), f2bf(v.y), f2bf(v.z), f2bf(v.w) };
            *(uint2*)(Wb + (size_t)row * 768 + c4 * 4) = *(uint2*)p;
        } else {
            int j = i - NT1 - NT2;
            int bh = j / (64 * 63), rem = j - bh * (64 * 63);
            int d = rem / 63, key = 577 + (rem - d * 63);
            size_t off = (((size_t)bh * 20 + (key >> 5)) * 4 + (d >> 4)) * 512
                       + (d & 15) * 32 + ((key >> 3) & 3) * 8 + (key & 7);
            Vf[off] = 0;
        }
    }
}

// ---------- qkv_gemm: BK=64, swizzled LDS, XCD-chunked tile order ----------
__global__ __launch_bounds__(256) void qkv_gemm(
    const unsigned short* __restrict__ Xb, const unsigned short* __restrict__ Wb,
    const float* __restrict__ bq, const float* __restrict__ bk, const float* __restrict__ bv,
    unsigned short* __restrict__ Qf, unsigned short* __restrict__ Kf,
    unsigned short* __restrict__ Vf)
{
    __shared__ unsigned short Als[128 * 64];
    __shared__ unsigned short Bls[128 * 64];

    // XCD-chunked: each XCD owns a 10-mt stripe; within it, (2mt x 18nt) groups
    // keep working set (2 Xb panels + whole Wb = 3.9 MB) inside one 4MB L2.
    const int bid = blockIdx.x;                 // grid 1440 = 8 XCD * 180
    const int xcd = bid & 7, sq = bid >> 3;     // sq 0..179
    const int mtg = sq / 36, rem = sq - mtg * 36;
    const int nt  = rem % 18;
    const int mt  = xcd * 10 + mtg * 2 + rem / 18;
    if (mt >= 73) return;

    const bool qk = (nt < 12);
    const int tid = threadIdx.x, lane = tid & 63, wid = tid >> 6;
    const int wm = wid >> 1, wn = wid & 1;
    const int m0 = mt * 128, n0 = nt * 128;
    const int l15 = lane & 15, g = lane >> 4;
    const int prow = lane >> 3, pc8 = lane & 7;

    const unsigned short* Pa = qk ? Bls : Als;   // A-operand rows (W for Q/K, X for V)
    const unsigned short* Pb = qk ? Als : Bls;

    f32x4 acc[4][4] = {};

    for (int kk = 0; kk < 768; kk += 64) {
        __syncthreads();
        #pragma unroll
        for (int t = 0; t < 4; ++t) {
            int row  = wid * 32 + t * 8 + prow;
            int scol = ((pc8 ^ (row & 7)) * 8);
            gll16(Xb + (size_t)(m0 + row) * 768 + kk + scol, &Als[(wid * 32 + t * 8) * 64]);
            gll16(Wb + (size_t)(n0 + row) * 768 + kk + scol, &Bls[(wid * 32 + t * 8) * 64]);
        }
        __syncthreads();

        #pragma unroll
        for (int ks = 0; ks < 2; ++ks) {
            short8 fa[4], fb[4];
            #pragma unroll
            for (int i = 0; i < 4; ++i) {
                int row = wm * 64 + i * 16 + l15;
                fa[i] = *(const short8*)&Pa[row * 64 + (((ks * 4 + g) ^ (row & 7)) * 8)];
            }
            #pragma unroll
            for (int j = 0; j < 4; ++j) {
                int row = wn * 64 + j * 16 + l15;
                fb[j] = *(const short8*)&Pb[row * 64 + (((ks * 4 + g) ^ (row & 7)) * 8)];
            }
            #pragma unroll
            for (int i = 0; i < 4; ++i)
                #pragma unroll
                for (int j = 0; j < 4; ++j)
                    acc[i][j] = __builtin_amdgcn_mfma_f32_16x16x32_bf16(fa[i], fb[j], acc[i][j], 0, 0, 0);
        }
    }

    if (qk) {
        // D rows = n (d-dim), cols = m. Pack 4 consecutive d per uint2 store.
        const float* bb = (nt < 6) ? bq : bk;
        unsigned short* Dst = (nt < 6) ? Qf : Kf;
        const float scale = (nt < 6) ? QSCALE : 1.0f;
        #pragma unroll
        for (int i = 0; i < 4; ++i) {
            int nrow0 = n0 - ((nt < 6) ? 0 : 768) + wm * 64 + i * 16 + g * 4;  // 4-aligned
            float4 b4 = *(const float4*)(bb + nrow0);
            int hh = nrow0 >> 6, d0 = nrow0 & 63;
            int dh5 = d0 >> 5;
            int dsub = ((d0 >> 3) & 3) * 8 + (d0 & 7);
            #pragma unroll
            for (int j = 0; j < 4; ++j) {
                int m = m0 + wn * 64 + j * 16 + l15;
                if (m >= M_) continue;
                int b = m / 577, s = m - b * 577;
                unsigned short p[4];
                p[0] = f2bf((acc[i][j][0] + b4.x) * scale);
                p[1] = f2bf((acc[i][j][1] + b4.y) * scale);
                p[2] = f2bf((acc[i][j][2] + b4.z) * scale);
                p[3] = f2bf((acc[i][j][3] + b4.w) * scale);
                size_t off;
                if (nt < 6)
                    off = (((size_t)(b * 40 + (s >> 4)) * 12 + hh) * 2 + dh5) * 512
                        + (s & 15) * 32 + dsub;
                else
                    off = ((((size_t)(b * 12 + hh)) * 10 + (s >> 6)) * 8 + ((s >> 4) & 3) * 2 + dh5) * 512
                        + (s & 15) * 32 + dsub;
                *(uint2*)(Dst + off) = *(uint2*)p;
            }
        }
    } else {
        // V: D rows = m (s), cols = n (d); scatter shorts into Vf
        #pragma unroll
        for (int j = 0; j < 4; ++j) {
            int n = n0 + wn * 64 + j * 16 + l15;
            int nn = n - 1536;
            float bias = bv[nn];
            int hh = nn >> 6, dwh = nn & 63;
            #pragma unroll
            for (int i = 0; i < 4; ++i) {
                #pragma unroll
                for (int r = 0; r < 4; ++r) {
                    int m = m0 + wm * 64 + i * 16 + g * 4 + r;
                    if (m >= M_) continue;
                    int b = m / 577, s = m - b * 577;
                    float val = acc[i][j][r] + bias;
                    size_t off = (((size_t)(b * 12 + hh) * 20 + (s >> 5)) * 4 + (dwh >> 4)) * 512
                               + (dwh & 15) * 32 + ((s >> 3) & 3) * 8 + (s & 7);
                    Vf[off] = f2bf(val);
                }
            }
        }
    }
}

// ---------- attn: QK -> reg softmax -> PV with fused nontemporal probs write ----------
__global__ __launch_bounds__(256) void attn(
    const unsigned short* __restrict__ Qf, const unsigned short* __restrict__ Kf,
    const unsigned short* __restrict__ Vf,
    float* __restrict__ ctx, float* __restrict__ probs)
{
    __shared__ unsigned short sc[16 * SCS];
    __shared__ float rowinv[16];

    const int wg  = blockIdx.x;                 // 7104 = 8 * 888, bijective XCD swizzle
    const int idx = (wg & 7) * 888 + (wg >> 3);
    const int bh  = idx / 37;
    const int qt  = idx - bh * 37;
    const int h   = bh % 12, b = bh / 12;

    const int tid = threadIdx.x, lane = tid & 63, wid = tid >> 6;
    const int l15 = lane & 15, g = lane >> 4;
    const int q0 = qt * 16;
    const int lofs = l15 * 32 + g * 8;

    const unsigned short* qb = Qf + ((size_t)(b * 40 + qt) * 12 + h) * 1024 + lofs;
    short8 aq0 = *(const short8*)qb;
    short8 aq1 = *(const short8*)(qb + 512);

    const unsigned short* kb0 = Kf + (size_t)bh * 40960 + wid * 1024 + lofs;
    #pragma unroll
    for (int c = 0; c < 10; ++c) {
        const unsigned short* kb = kb0 + c * 4096;
        short8 bk0 = *(const short8*)kb;
        short8 bk1 = *(const short8*)(kb + 512);
        f32x4 s4 = {};
        s4 = __builtin_amdgcn_mfma_f32_16x16x32_bf16(aq0, bk0, s4, 0, 0, 0);
        s4 = __builtin_amdgcn_mfma_f32_16x16x32_bf16(aq1, bk1, s4, 0, 0, 0);
        int key = c * 64 + wid * 16 + l15;
        #pragma unroll
        for (int r = 0; r < 4; ++r)
            sc[(g * 4 + r) * SCS + key] = (key < S_) ? f2bf(s4[r]) : (unsigned short)0xFF80u; // -inf
    }
    __syncthreads();

    // softmax (log2 domain): 16 threads per row; score chunk held in registers
    {
        const int r = tid >> 4, c0 = tid & 15;
        unsigned short* row = &sc[r * SCS];
        short8 v[5];
        float m = -1e30f;
        #pragma unroll
        for (int i = 0; i < 5; ++i) {
            v[i] = *(const short8*)&row[(c0 + 16 * i) * 8];
            #pragma unroll
            for (int jj = 0; jj < 8; ++jj) m = fmaxf(m, bf2f((unsigned short)v[i][jj]));
        }
        #pragma unroll
        for (int o = 8; o; o >>= 1) m = fmaxf(m, __shfl_xor(m, o));

        float ssum = 0.f;
        #pragma unroll
        for (int i = 0; i < 5; ++i) {
            short8 w;
            #pragma unroll
            for (int jj = 0; jj < 8; ++jj) {
                float e = exp2f(bf2f((unsigned short)v[i][jj]) - m);
                ssum += e;
                w[jj] = (short)f2bf(e);
            }
            *(short8*)&row[(c0 + 16 * i) * 8] = w;
        }
        #pragma unroll
        for (int o = 8; o; o >>= 1) ssum += __shfl_xor(ssum, o);
        if (c0 == 0) rowinv[r] = 1.0f / ssum;
    }
    __syncthreads();

    // PV with fused probs write: ap fragments already hold every e-value.
    // Wave wid stores chunks kk%4==wid; stores drain under the MFMA stream.
    f32x4 oc = {};
    const unsigned short* vb0 = Vf + (size_t)bh * 40960 + wid * 512 + lofs;
    const unsigned short* pb  = &sc[l15 * SCS + g * 8];
    const bool qvalid = (q0 + l15) < S_;
    const float pinv = rowinv[l15];
    float* prow = probs + ((size_t)bh * S_ + q0 + l15) * S_;
    #pragma unroll
    for (int kk = 0; kk < 20; ++kk) {
        short8 ap = *(const short8*)(pb + kk * 32);
        short8 bv = *(const short8*)(vb0 + kk * 2048);
        oc = __builtin_amdgcn_mfma_f32_16x16x32_bf16(ap, bv, oc, 0, 0, 0);
        if ((kk & 3) == wid) {
            int kbase = kk * 32 + g * 8;
            if (qvalid) {
                if (kbase + 7 < S_) {          // kk <= 17: full 8-float run
                    f32x4 o0, o1;
                    o0[0] = bf2f((unsigned short)ap[0]) * pinv; o0[1] = bf2f((unsigned short)ap[1]) * pinv;
                    o0[2] = bf2f((unsigned short)ap[2]) * pinv; o0[3] = bf2f((unsigned short)ap[3]) * pinv;
                    o1[0] = bf2f((unsigned short)ap[4]) * pinv; o1[1] = bf2f((unsigned short)ap[5]) * pinv;
                    o1[2] = bf2f((unsigned short)ap[6]) * pinv; o1[3] = bf2f((unsigned short)ap[7]) * pinv;
                    __builtin_nontemporal_store(o0, (f32x4*)&prow[kbase]);
                    __builtin_nontemporal_store(o1, (f32x4*)&prow[kbase + 4]);
                } else if (kbase < S_) {       // kk==18, g==0: single tail float
                    __builtin_nontemporal_store(bf2f((unsigned short)ap[0]) * pinv, &prow[576]);
                }
            }
        }
    }
    #pragma unroll
    for (int rr = 0; rr < 4; ++rr) {
        int qr = g * 4 + rr;
        int qq = q0 + qr;
        if (qq < S_)
            __builtin_nontemporal_store(oc[rr] * rowinv[qr],
                &ctx[((size_t)b * S_ + qq) * D_ + h * 64 + wid * 16 + l15]);
    }
}

extern "C" void kernel_launch(void* const* d_in, const int* in_sizes, int n_in,
                              void* d_out, int out_size, void* d_ws, size_t ws_size,
                              hipStream_t stream) {
    const float* X  = (const float*)d_in[0];
    const float* Wq = (const float*)d_in[1];
    const float* bq = (const float*)d_in[2];
    const float* Wk = (const float*)d_in[3];
    const float* bk = (const float*)d_in[4];
    const float* Wv = (const float*)d_in[5];
    const float* bv = (const float*)d_in[6];

    float* ctx   = (float*)d_out;
    float* probs = ctx + (size_t)B_ * S_ * D_;

    unsigned short* Xb = (unsigned short*)probs;            // staged in probs region
    unsigned short* Wb = Xb + (size_t)MP * 768;

    unsigned short* Qf = (unsigned short*)d_ws;
    unsigned short* Kf = Qf + (size_t)7864320;
    unsigned short* Vf = Kf + (size_t)7864320;

    prep<<<dim3(1024), 256, 0, stream>>>(X, Wq, Wk, Wv, Xb, Wb, Vf);
    qkv_gemm<<<dim3(1440), 256, 0, stream>>>(Xb, Wb, bq, bk, bv, Qf, Kf, Vf);
    attn<<<dim3(7104), 256, 0, stream>>>(Qf, Kf, Vf, ctx, probs);
}

// Round 7
// 213.676 us; speedup vs baseline: 1.7536x; 1.7536x over previous
//
#include <hip/hip_runtime.h>
#include <hip/hip_bf16.h>
#include <cstdint>

#define B_  16
#define S_  577
#define D_  768
#define H_  12
#define SP  640           // padded S
#define M_  (B_*S_)       // 9232
#define MP  9344          // padded M (73*128)
#define N_  2304          // combined QKV output dim
#define SCS 664           // sc LDS stride in shorts
#define QSCALE 0.18033688011112042f   // 0.125 * log2(e): scores land in log2 domain

typedef __attribute__((ext_vector_type(8))) short short8;
typedef __attribute__((ext_vector_type(4))) float f32x4;

static __device__ __forceinline__ unsigned short f2bf(float f) {
    uint32_t u = __builtin_bit_cast(uint32_t, f);
    uint32_t r = u + 0x7fffu + ((u >> 16) & 1u);
    return (unsigned short)(r >> 16);
}
static __device__ __forceinline__ float bf2f(unsigned short u) {
    uint32_t x = ((uint32_t)u) << 16;
    return __builtin_bit_cast(float, x);
}

typedef unsigned int u32;
typedef __attribute__((address_space(3))) u32 lds_u32;
typedef __attribute__((address_space(1))) const u32 gbl_u32;
static __device__ __forceinline__ void gll16(const void* g, void* l) {
    __builtin_amdgcn_global_load_lds((gbl_u32*)g, (lds_u32*)l, 16, 0, 0);
}

// Fragment layouts (shorts), d = within-head dim (0..63):
//  Qf: (((b*40+qc)*12+h)*2+dh)*512 + ql*32 + dg*8 + db      q=qc*16+ql, d=dh*32+dg*8+db
//  Kf: (((b*12+h)*10+c)*4+kq)*2+dh)*512 + kl*32 + dg*8 + db key=c*64+kq*16+kl
//  Vf: ((b*12+h)*20+kk)*4+wq)*512 + dl*32 + kg*8 + kb       key=kk*32+kg*8+kb, d=wq*16+dl
// Each attn wave fragment load = contiguous 1KB.

// ---------- prep: fp32 -> bf16 of X (zero pad rows) and W; zero Vf pad keys ----------
__global__ __launch_bounds__(256) void prep(
    const float* __restrict__ X,
    const float* __restrict__ Wq, const float* __restrict__ Wk, const float* __restrict__ Wv,
    unsigned short* __restrict__ Xb, unsigned short* __restrict__ Wb,
    unsigned short* __restrict__ Vf)
{
    const int NT1 = MP * 192;
    const int NT2 = N_ * 192;
    const int VPAD = 192 * 64 * 63;            // (b*h) * d * padkeys
    const int total = NT1 + NT2 + VPAD;
    const int stride = gridDim.x * 256;
    for (int i = blockIdx.x * 256 + threadIdx.x; i < total; i += stride) {
        if (i < NT1) {
            int row = i / 192, c4 = i - row * 192;
            uint2 out = make_uint2(0u, 0u);
            if (row < M_) {
                float4 v = *(const float4*)(X + (size_t)row * 768 + c4 * 4);
                unsigned short p[4] = { f2bf(v.x), f2bf(v.y), f2bf(v.z), f2bf(v.w) };
                out = *(uint2*)p;
            }
            *(uint2*)(Xb + (size_t)row * 768 + c4 * 4) = out;
        } else if (i < NT1 + NT2) {
            int j = i - NT1;
            int row = j / 192, c4 = j - row * 192;
            const float* src = (row < 768) ? (Wq + (size_t)row * 768)
                             : (row < 1536) ? (Wk + (size_t)(row - 768) * 768)
                                            : (Wv + (size_t)(row - 1536) * 768);
            float4 v = *(const float4*)(src + c4 * 4);
            unsigned short p[4] = { f2bf(v.x), f2bf(v.y), f2bf(v.z), f2bf(v.w) };
            *(uint2*)(Wb + (size_t)row * 768 + c4 * 4) = *(uint2*)p;
        } else {
            int j = i - NT1 - NT2;
            int bh = j / (64 * 63), rem = j - bh * (64 * 63);
            int d = rem / 63, key = 577 + (rem - d * 63);
            size_t off = (((size_t)bh * 20 + (key >> 5)) * 4 + (d >> 4)) * 512
                       + (d & 15) * 32 + ((key >> 3) & 3) * 8 + (key & 7);
            Vf[off] = 0;
        }
    }
}

// ---------- qkv_gemm: BK=64, swizzled LDS, XCD-chunked tile order ----------
__global__ __launch_bounds__(256) void qkv_gemm(
    const unsigned short* __restrict__ Xb, const unsigned short* __restrict__ Wb,
    const float* __restrict__ bq, const float* __restrict__ bk, const float* __restrict__ bv,
    unsigned short* __restrict__ Qf, unsigned short* __restrict__ Kf,
    unsigned short* __restrict__ Vf)
{
    __shared__ unsigned short Als[128 * 64];
    __shared__ unsigned short Bls[128 * 64];

    // XCD-chunked: each XCD owns a 10-mt stripe; within it, (2mt x 18nt) groups
    // keep working set (2 Xb panels + whole Wb = 3.9 MB) inside one 4MB L2.
    const int bid = blockIdx.x;                 // grid 1440 = 8 XCD * 180
    const int xcd = bid & 7, sq = bid >> 3;     // sq 0..179
    const int mtg = sq / 36, rem = sq - mtg * 36;
    const int nt  = rem % 18;
    const int mt  = xcd * 10 + mtg * 2 + rem / 18;
    if (mt >= 73) return;

    const bool qk = (nt < 12);
    const int tid = threadIdx.x, lane = tid & 63, wid = tid >> 6;
    const int wm = wid >> 1, wn = wid & 1;
    const int m0 = mt * 128, n0 = nt * 128;
    const int l15 = lane & 15, g = lane >> 4;
    const int prow = lane >> 3, pc8 = lane & 7;

    const unsigned short* Pa = qk ? Bls : Als;   // A-operand rows (W for Q/K, X for V)
    const unsigned short* Pb = qk ? Als : Bls;

    f32x4 acc[4][4] = {};

    for (int kk = 0; kk < 768; kk += 64) {
        __syncthreads();
        #pragma unroll
        for (int t = 0; t < 4; ++t) {
            int row  = wid * 32 + t * 8 + prow;
            int scol = ((pc8 ^ (row & 7)) * 8);
            gll16(Xb + (size_t)(m0 + row) * 768 + kk + scol, &Als[(wid * 32 + t * 8) * 64]);
            gll16(Wb + (size_t)(n0 + row) * 768 + kk + scol, &Bls[(wid * 32 + t * 8) * 64]);
        }
        __syncthreads();

        #pragma unroll
        for (int ks = 0; ks < 2; ++ks) {
            short8 fa[4], fb[4];
            #pragma unroll
            for (int i = 0; i < 4; ++i) {
                int row = wm * 64 + i * 16 + l15;
                fa[i] = *(const short8*)&Pa[row * 64 + (((ks * 4 + g) ^ (row & 7)) * 8)];
            }
            #pragma unroll
            for (int j = 0; j < 4; ++j) {
                int row = wn * 64 + j * 16 + l15;
                fb[j] = *(const short8*)&Pb[row * 64 + (((ks * 4 + g) ^ (row & 7)) * 8)];
            }
            #pragma unroll
            for (int i = 0; i < 4; ++i)
                #pragma unroll
                for (int j = 0; j < 4; ++j)
                    acc[i][j] = __builtin_amdgcn_mfma_f32_16x16x32_bf16(fa[i], fb[j], acc[i][j], 0, 0, 0);
        }
    }

    if (qk) {
        // D rows = n (d-dim), cols = m. Pack 4 consecutive d per uint2 store.
        const float* bb = (nt < 6) ? bq : bk;
        unsigned short* Dst = (nt < 6) ? Qf : Kf;
        const float scale = (nt < 6) ? QSCALE : 1.0f;
        #pragma unroll
        for (int i = 0; i < 4; ++i) {
            int nrow0 = n0 - ((nt < 6) ? 0 : 768) + wm * 64 + i * 16 + g * 4;  // 4-aligned
            float4 b4 = *(const float4*)(bb + nrow0);
            int hh = nrow0 >> 6, d0 = nrow0 & 63;
            int dh5 = d0 >> 5;
            int dsub = ((d0 >> 3) & 3) * 8 + (d0 & 7);
            #pragma unroll
            for (int j = 0; j < 4; ++j) {
                int m = m0 + wn * 64 + j * 16 + l15;
                if (m >= M_) continue;
                int b = m / 577, s = m - b * 577;
                unsigned short p[4];
                p[0] = f2bf((acc[i][j][0] + b4.x) * scale);
                p[1] = f2bf((acc[i][j][1] + b4.y) * scale);
                p[2] = f2bf((acc[i][j][2] + b4.z) * scale);
                p[3] = f2bf((acc[i][j][3] + b4.w) * scale);
                size_t off;
                if (nt < 6)
                    off = (((size_t)(b * 40 + (s >> 4)) * 12 + hh) * 2 + dh5) * 512
                        + (s & 15) * 32 + dsub;
                else
                    off = ((((size_t)(b * 12 + hh)) * 10 + (s >> 6)) * 8 + ((s >> 4) & 3) * 2 + dh5) * 512
                        + (s & 15) * 32 + dsub;
                *(uint2*)(Dst + off) = *(uint2*)p;
            }
        }
    } else {
        // V: D rows = m (s), cols = n (d); scatter shorts into Vf
        #pragma unroll
        for (int j = 0; j < 4; ++j) {
            int n = n0 + wn * 64 + j * 16 + l15;
            int nn = n - 1536;
            float bias = bv[nn];
            int hh = nn >> 6, dwh = nn & 63;
            #pragma unroll
            for (int i = 0; i < 4; ++i) {
                #pragma unroll
                for (int r = 0; r < 4; ++r) {
                    int m = m0 + wm * 64 + i * 16 + g * 4 + r;
                    if (m >= M_) continue;
                    int b = m / 577, s = m - b * 577;
                    float val = acc[i][j][r] + bias;
                    size_t off = (((size_t)(b * 12 + hh) * 20 + (s >> 5)) * 4 + (dwh >> 4)) * 512
                               + (dwh & 15) * 32 + ((s >> 3) & 3) * 8 + (s & 7);
                    Vf[off] = f2bf(val);
                }
            }
        }
    }
}

// ---------- attn: QK -> reg softmax -> coalesced nt probs write -> PV ----------
__global__ __launch_bounds__(256) void attn(
    const unsigned short* __restrict__ Qf, const unsigned short* __restrict__ Kf,
    const unsigned short* __restrict__ Vf,
    float* __restrict__ ctx, float* __restrict__ probs)
{
    __shared__ unsigned short sc[16 * SCS];
    __shared__ float rowinv[16];

    const int wg  = blockIdx.x;                 // 7104 = 8 * 888, bijective XCD swizzle
    const int idx = (wg & 7) * 888 + (wg >> 3);
    const int bh  = idx / 37;
    const int qt  = idx - bh * 37;
    const int h   = bh % 12, b = bh / 12;

    const int tid = threadIdx.x, lane = tid & 63, wid = tid >> 6;
    const int l15 = lane & 15, g = lane >> 4;
    const int q0 = qt * 16;
    const int lofs = l15 * 32 + g * 8;

    const unsigned short* qb = Qf + ((size_t)(b * 40 + qt) * 12 + h) * 1024 + lofs;
    short8 aq0 = *(const short8*)qb;
    short8 aq1 = *(const short8*)(qb + 512);

    const unsigned short* kb0 = Kf + (size_t)bh * 40960 + wid * 1024 + lofs;
    #pragma unroll
    for (int c = 0; c < 10; ++c) {
        const unsigned short* kb = kb0 + c * 4096;
        short8 bk0 = *(const short8*)kb;
        short8 bk1 = *(const short8*)(kb + 512);
        f32x4 s4 = {};
        s4 = __builtin_amdgcn_mfma_f32_16x16x32_bf16(aq0, bk0, s4, 0, 0, 0);
        s4 = __builtin_amdgcn_mfma_f32_16x16x32_bf16(aq1, bk1, s4, 0, 0, 0);
        int key = c * 64 + wid * 16 + l15;
        #pragma unroll
        for (int r = 0; r < 4; ++r)
            sc[(g * 4 + r) * SCS + key] = (key < S_) ? f2bf(s4[r]) : (unsigned short)0xFF80u; // -inf
    }
    __syncthreads();

    // softmax (log2 domain): 16 threads per row; scores AND e-values in registers
    const int r = tid >> 4, c0 = tid & 15;
    unsigned short* row = &sc[r * SCS];
    float ev[40];                       // e-values stay for the probs write
    {
        short8 v[5];
        float m = -1e30f;
        #pragma unroll
        for (int i = 0; i < 5; ++i) {
            v[i] = *(const short8*)&row[(c0 + 16 * i) * 8];
            #pragma unroll
            for (int jj = 0; jj < 8; ++jj) m = fmaxf(m, bf2f((unsigned short)v[i][jj]));
        }
        #pragma unroll
        for (int o = 8; o; o >>= 1) m = fmaxf(m, __shfl_xor(m, o));

        float ssum = 0.f;
        #pragma unroll
        for (int i = 0; i < 5; ++i) {
            short8 w;
            #pragma unroll
            for (int jj = 0; jj < 8; ++jj) {
                float e = exp2f(bf2f((unsigned short)v[i][jj]) - m);
                ev[i * 8 + jj] = e;
                ssum += e;
                w[jj] = (short)f2bf(e);
            }
            *(short8*)&row[(c0 + 16 * i) * 8] = w;
        }
        #pragma unroll
        for (int o = 8; o; o >>= 1) ssum += __shfl_xor(ssum, o);
        if (c0 == 0) rowinv[r] = 1.0f / ssum;

        // probs write straight from registers: lane writes 32B contiguous runs,
        // 16 adjacent lanes cover 512B per row -> sector-complete nt stores.
        float inv = 1.0f / ssum;
        int q = q0 + r;
        if (q < S_) {
            float* prow = probs + ((size_t)bh * S_ + q) * S_;
            #pragma unroll
            for (int i = 0; i < 5; ++i) {
                int ch = c0 + 16 * i;
                if (ch < 72) {
                    f32x4 o0, o1;
                    o0[0] = ev[i*8+0] * inv; o0[1] = ev[i*8+1] * inv;
                    o0[2] = ev[i*8+2] * inv; o0[3] = ev[i*8+3] * inv;
                    o1[0] = ev[i*8+4] * inv; o1[1] = ev[i*8+5] * inv;
                    o1[2] = ev[i*8+6] * inv; o1[3] = ev[i*8+7] * inv;
                    __builtin_nontemporal_store(o0, (f32x4*)&prow[ch * 8]);
                    __builtin_nontemporal_store(o1, (f32x4*)&prow[ch * 8 + 4]);
                } else if (ch == 72) {
                    __builtin_nontemporal_store(ev[i*8] * inv, &prow[576]);
                }
            }
        }
    }
    __syncthreads();

    // PV: wave wid owns d-slice [wid*16, wid*16+16)
    f32x4 oc = {};
    const unsigned short* vb0 = Vf + (size_t)bh * 40960 + wid * 512 + lofs;
    const unsigned short* pb  = &sc[l15 * SCS + g * 8];
    #pragma unroll
    for (int kk = 0; kk < 20; ++kk) {
        short8 ap = *(const short8*)(pb + kk * 32);
        short8 bv = *(const short8*)(vb0 + kk * 2048);
        oc = __builtin_amdgcn_mfma_f32_16x16x32_bf16(ap, bv, oc, 0, 0, 0);
    }
    #pragma unroll
    for (int rr = 0; rr < 4; ++rr) {
        int qr = g * 4 + rr;
        int qq = q0 + qr;
        if (qq < S_)
            __builtin_nontemporal_store(oc[rr] * rowinv[qr],
                &ctx[((size_t)b * S_ + qq) * D_ + h * 64 + wid * 16 + l15]);
    }
}

extern "C" void kernel_launch(void* const* d_in, const int* in_sizes, int n_in,
                              void* d_out, int out_size, void* d_ws, size_t ws_size,
                              hipStream_t stream) {
    const float* X  = (const float*)d_in[0];
    const float* Wq = (const float*)d_in[1];
    const float* bq = (const float*)d_in[2];
    const float* Wk = (const float*)d_in[3];
    const float* bk = (const float*)d_in[4];
    const float* Wv = (const float*)d_in[5];
    const float* bv = (const float*)d_in[6];

    float* ctx   = (float*)d_out;
    float* probs = ctx + (size_t)B_ * S_ * D_;

    unsigned short* Xb = (unsigned short*)probs;            // staged in probs region
    unsigned short* Wb = Xb + (size_t)MP * 768;

    unsigned short* Qf = (unsigned short*)d_ws;
    unsigned short* Kf = Qf + (size_t)7864320;
    unsigned short* Vf = Kf + (size_t)7864320;

    prep<<<dim3(1024), 256, 0, stream>>>(X, Wq, Wk, Wv, Xb, Wb, Vf);
    qkv_gemm<<<dim3(1440), 256, 0, stream>>>(Xb, Wb, bq, bk, bv, Qf, Kf, Vf);
    attn<<<dim3(7104), 256, 0, stream>>>(Qf, Kf, Vf, ctx, probs);
}